// Round 1
// baseline (211.711 us; speedup 1.0000x reference)
//
#include <hip/hip_runtime.h>
#include <cstddef>

// ---------------------------------------------------------------------------
// GraphSAGE-style block:
//   y[b,j,:]   = relu(W1 @ x[b,:,j] + b1)              (per-NODE, not per-edge!)
//   m[b,n,:]   = max_k y[b, idx[b,n,k], :]
//   out[b,:,n] = relu(W2 @ concat(x[b,:,n], m[b,n,:]) + b2)
// ---------------------------------------------------------------------------

__device__ __forceinline__ float4 fmax4(float4 a, float4 b) {
  return make_float4(fmaxf(a.x, b.x), fmaxf(a.y, b.y),
                     fmaxf(a.z, b.z), fmaxf(a.w, b.w));
}

// Detect whether the edge_index buffer is int64 (little-endian: odd 32-bit
// words all zero for values < 2^31) or already int32.
__global__ void detect_idx_kernel(const int* __restrict__ e, int* __restrict__ flag) {
  if (threadIdx.x == 0 && blockIdx.x == 0) {
    int hi_zero = 1;
    for (int i = 0; i < 64; ++i) hi_zero &= (e[2 * i + 1] == 0) ? 1 : 0;
    *flag = hi_zero;  // 1 => int64 layout (stride 2), 0 => int32 (stride 1)
  }
}

// K1: y[(b*N+n)*64 + d] = relu(b1[d] + sum_c W1[d*64+c] * x[(b*64+c)*N + n])
// Block: 256 threads, 64 nodes. LDS: x-tile [c][n] + W1^T [c][d] = 32 KB.
__global__ __launch_bounds__(256) void k1_node_mlp(
    const float* __restrict__ x, const float* __restrict__ W1,
    const float* __restrict__ b1, float* __restrict__ y, int N)
{
  __shared__ __align__(16) float xs[64 * 64];  // [c][n]
  __shared__ __align__(16) float wt[64 * 64];  // [c][d] = W1[d][c]
  const int t = threadIdx.x;
  const int nblk = (N + 63) >> 6;
  const int b = blockIdx.x / nblk;
  const int n0 = (blockIdx.x % nblk) << 6;

  // Stage x tile: lanes along n (coalesced 256B), each wave covers 16 c-rows.
  {
    const int n = t & 63;
    const int cw = (t >> 6) << 4;
    const bool valid = (n0 + n) < N;
    const float* xp = x + (size_t)b * 64 * N + n0 + n;
#pragma unroll
    for (int it = 0; it < 16; ++it) {
      const int c = cw + it;
      xs[c * 64 + n] = valid ? xp[(size_t)c * N] : 0.0f;
    }
  }
  // Stage W1 transposed (strided global reads, L2-hit; conflict-free LDS writes).
#pragma unroll
  for (int it = 0; it < 16; ++it) {
    const int i = t + (it << 8);
    const int d = i & 63, c = i >> 6;
    wt[c * 64 + d] = W1[d * 64 + c];
  }
  __syncthreads();

  // Register-blocked 4x4 tile per thread: n_off = (t%16)*4, d0 = (t/16)*4
  const int n_off = (t & 15) << 2;
  const int d0 = (t >> 4) << 2;
  float acc[4][4];
#pragma unroll
  for (int i = 0; i < 4; ++i) {
    const float bv = b1[d0 + i];
#pragma unroll
    for (int j = 0; j < 4; ++j) acc[i][j] = bv;
  }
#pragma unroll 4
  for (int c = 0; c < 64; ++c) {
    const float4 w = *(const float4*)(wt + c * 64 + d0);
    const float4 xv = *(const float4*)(xs + c * 64 + n_off);
    const float wa[4] = {w.x, w.y, w.z, w.w};
    const float xa[4] = {xv.x, xv.y, xv.z, xv.w};
#pragma unroll
    for (int i = 0; i < 4; ++i)
#pragma unroll
      for (int j = 0; j < 4; ++j)
        acc[i][j] = fmaf(wa[i], xa[j], acc[i][j]);
  }
  // Store y node-major: row n = 256B contiguous (gather-friendly).
#pragma unroll
  for (int j = 0; j < 4; ++j) {
    const int n = n0 + n_off + j;
    if (n < N) {
      float4 v = make_float4(fmaxf(acc[0][j], 0.f), fmaxf(acc[1][j], 0.f),
                             fmaxf(acc[2][j], 0.f), fmaxf(acc[3][j], 0.f));
      *(float4*)(y + ((size_t)b * N + n) * 64 + d0) = v;
    }
  }
}

// K2: gather-max over y rows, then out = relu(W2 @ [x; m] + b2).
// Block: 256 threads, 64 nodes. LDS: ins[128c][64n] + W2^T[128c][64o] = 64 KB.
__global__ __launch_bounds__(256) void k2_gather_out(
    const float* __restrict__ x, const int* __restrict__ eidx,
    const float* __restrict__ y, const float* __restrict__ W2,
    const float* __restrict__ b2, float* __restrict__ out,
    int N, int K, const int* __restrict__ is64)
{
  __shared__ __align__(16) float ins[128 * 64];  // [c][n]: c<64 = x, c>=64 = m
  __shared__ __align__(16) float wt[128 * 64];   // [c][o] = W2[o][c]
  const int t = threadIdx.x;
  const int nblk = (N + 63) >> 6;
  const int b = blockIdx.x / nblk;
  const int n0 = (blockIdx.x % nblk) << 6;

  // Phase A: stage x tile (rows 0..63 of ins).
  {
    const int n = t & 63;
    const int cw = (t >> 6) << 4;
    const bool valid = (n0 + n) < N;
    const float* xp = x + (size_t)b * 64 * N + n0 + n;
#pragma unroll
    for (int it = 0; it < 16; ++it) {
      const int c = cw + it;
      ins[c * 64 + n] = valid ? xp[(size_t)c * N] : 0.0f;
    }
  }
  // Stage W2 transposed.
#pragma unroll
  for (int it = 0; it < 32; ++it) {
    const int i = t + (it << 8);
    const int o = i & 63, c = i >> 6;
    wt[c * 64 + o] = W2[o * 128 + c];
  }
  // Phase B: gather-max. Lanes along node => conflict-free LDS writes.
  // Each wave covers a 16-wide d-slice; per-thread 9*4 scattered float4 loads.
  {
    const int node = t & 63;
    const int dr = (t >> 6) << 4;
    float4 m0 = make_float4(0.f, 0.f, 0.f, 0.f);  // relu'd y >= 0, init 0 safe
    float4 m1 = m0, m2 = m0, m3 = m0;
    const int n = n0 + node;
    if (n < N) {
      const int stride = (*is64) ? 2 : 1;
      const int* ep = eidx + (size_t)(b * N + n) * K * stride;
      for (int k = 0; k < K; ++k) {
        const int j = ep[k * stride];
        const float4* yr = (const float4*)(y + ((size_t)b * N + j) * 64 + dr);
        m0 = fmax4(m0, yr[0]);
        m1 = fmax4(m1, yr[1]);
        m2 = fmax4(m2, yr[2]);
        m3 = fmax4(m3, yr[3]);
      }
    }
    ins[(64 + dr + 0) * 64 + node] = m0.x;
    ins[(64 + dr + 1) * 64 + node] = m0.y;
    ins[(64 + dr + 2) * 64 + node] = m0.z;
    ins[(64 + dr + 3) * 64 + node] = m0.w;
    ins[(64 + dr + 4) * 64 + node] = m1.x;
    ins[(64 + dr + 5) * 64 + node] = m1.y;
    ins[(64 + dr + 6) * 64 + node] = m1.z;
    ins[(64 + dr + 7) * 64 + node] = m1.w;
    ins[(64 + dr + 8) * 64 + node] = m2.x;
    ins[(64 + dr + 9) * 64 + node] = m2.y;
    ins[(64 + dr + 10) * 64 + node] = m2.z;
    ins[(64 + dr + 11) * 64 + node] = m2.w;
    ins[(64 + dr + 12) * 64 + node] = m3.x;
    ins[(64 + dr + 13) * 64 + node] = m3.y;
    ins[(64 + dr + 14) * 64 + node] = m3.z;
    ins[(64 + dr + 15) * 64 + node] = m3.w;
  }
  __syncthreads();

  // Phase C: out[64o x 64n] = W2[64x128] * ins[128x64], 4x4 tile per thread.
  const int n_off = (t & 15) << 2;
  const int o0 = (t >> 4) << 2;
  float acc[4][4];
#pragma unroll
  for (int i = 0; i < 4; ++i) {
    const float bv = b2[o0 + i];
#pragma unroll
    for (int j = 0; j < 4; ++j) acc[i][j] = bv;
  }
#pragma unroll 4
  for (int c = 0; c < 128; ++c) {
    const float4 w = *(const float4*)(wt + c * 64 + o0);
    const float4 xv = *(const float4*)(ins + c * 64 + n_off);
    const float wa[4] = {w.x, w.y, w.z, w.w};
    const float xa[4] = {xv.x, xv.y, xv.z, xv.w};
#pragma unroll
    for (int i = 0; i < 4; ++i)
#pragma unroll
      for (int j = 0; j < 4; ++j)
        acc[i][j] = fmaf(wa[i], xa[j], acc[i][j]);
  }
  // Store: out[(b*64+o)*N + n], float4 over n (fully coalesced per o-row).
#pragma unroll
  for (int i = 0; i < 4; ++i) {
    const int o = o0 + i;
    float* op = out + (size_t)(b * 64 + o) * N + n0 + n_off;
    const float4 v = make_float4(fmaxf(acc[i][0], 0.f), fmaxf(acc[i][1], 0.f),
                                 fmaxf(acc[i][2], 0.f), fmaxf(acc[i][3], 0.f));
    if (n0 + n_off + 3 < N) {
      *(float4*)op = v;
    } else {
      const float va[4] = {v.x, v.y, v.z, v.w};
      for (int j = 0; j < 4; ++j)
        if (n0 + n_off + j < N) op[j] = va[j];
    }
  }
}

extern "C" void kernel_launch(void* const* d_in, const int* in_sizes, int n_in,
                              void* d_out, int out_size, void* d_ws, size_t ws_size,
                              hipStream_t stream) {
  const float* x  = (const float*)d_in[0];   // [B=2, C=64, N, 1]
  const int*   ei = (const int*)d_in[1];     // [2, B, N, K] (int32 or int64)
  const float* W1 = (const float*)d_in[2];   // [64, 64]
  const float* b1 = (const float*)d_in[3];   // [64]
  const float* W2 = (const float*)d_in[4];   // [64, 128]
  const float* b2 = (const float*)d_in[5];   // [64]
  float* out = (float*)d_out;                // [B, 64, N, 1]

  const int N = in_sizes[0] / 128;           // B*C = 128
  const int K = in_sizes[1] / (4 * N);       // 2*B = 4

  float* y = (float*)d_ws;                   // [B, N, 64] = 25.6 MB
  int* flag = (int*)((char*)d_ws + (size_t)2 * N * 64 * sizeof(float));

  const int nblk = (N + 63) >> 6;
  detect_idx_kernel<<<1, 64, 0, stream>>>(ei, flag);
  k1_node_mlp<<<2 * nblk, 256, 0, stream>>>(x, W1, b1, y, N);
  k2_gather_out<<<2 * nblk, 256, 0, stream>>>(x, ei, y, W2, b2, out, N, K, flag);
}

// Round 2
// 177.820 us; speedup vs baseline: 1.1906x; 1.1906x over previous
//
#include <hip/hip_runtime.h>
#include <cstddef>

typedef unsigned int uint;

// ---------------------------------------------------------------------------
// GraphSAGE-style block, restructured per-NODE (not per-edge):
//   y[b,j,:]   = relu(W1 @ x[b,:,j] + b1)      -> bf16 table [B,N,64], 128 B/row
//   m[b,n,:]   = max_k y[b, idx[b,n,k], :]     (relu'd => >= 0, uint16-safe max)
//   out[b,:,n] = relu(W2 @ concat(x[b,:,n], m[b,n,:]) + b2)
// ---------------------------------------------------------------------------

__device__ __forceinline__ unsigned short f2bf(float f) {  // RNE fp32 -> bf16
  union { float f; uint u; } v; v.f = f;
  uint r = (v.u + 0x7fffu + ((v.u >> 16) & 1u)) >> 16;
  return (unsigned short)r;
}
__device__ __forceinline__ float bflo(uint u) {  // low bf16 of a packed pair
  union { uint u; float f; } v; v.u = u << 16; return v.f;
}
__device__ __forceinline__ float bfhi(uint u) {  // high bf16 of a packed pair
  union { uint u; float f; } v; v.u = u & 0xffff0000u; return v.f;
}

// Detect int64 vs int32 edge_index layout: odd 32-bit words all zero => int64.
__global__ void detect_idx_kernel(const int* __restrict__ e, int* __restrict__ flag) {
  const int v = e[2 * threadIdx.x + 1];
  const unsigned long long b = __ballot(v == 0);
  if (threadIdx.x == 0) *flag = (b == ~0ull) ? 1 : 0;
}

// K1: y[b,n,:] = relu(W1 @ x[b,:,n] + b1), stored bf16 node-major (128 B rows).
__global__ __launch_bounds__(256) void k1_node_mlp(
    const float* __restrict__ x, const float* __restrict__ W1,
    const float* __restrict__ b1, unsigned short* __restrict__ y, int N)
{
  __shared__ __align__(16) float xs[64 * 64];  // [c][n]
  __shared__ __align__(16) float wt[64 * 64];  // [c][d] = W1[d][c]
  const int t = threadIdx.x;
  const int nblk = (N + 63) >> 6;
  const int b = blockIdx.x / nblk;
  const int n0 = (blockIdx.x % nblk) << 6;

  {  // stage x tile: lanes along n => coalesced 256 B per c-row
    const int n = t & 63;
    const int cw = (t >> 6) << 4;
    const bool valid = (n0 + n) < N;
    const float* xp = x + (size_t)b * 64 * N + n0 + n;
#pragma unroll
    for (int it = 0; it < 16; ++it) {
      const int c = cw + it;
      xs[c * 64 + n] = valid ? xp[(size_t)c * N] : 0.0f;
    }
  }
#pragma unroll
  for (int it = 0; it < 16; ++it) {  // W1^T (strided reads, L1/L2-hot)
    const int i = t + (it << 8);
    const int d = i & 63, c = i >> 6;
    wt[c * 64 + d] = W1[d * 64 + c];
  }
  __syncthreads();

  const int n_off = (t & 15) << 2;
  const int d0 = (t >> 4) << 2;
  float acc[4][4];
#pragma unroll
  for (int i = 0; i < 4; ++i) {
    const float bv = b1[d0 + i];
#pragma unroll
    for (int j = 0; j < 4; ++j) acc[i][j] = bv;
  }
#pragma unroll 4
  for (int c = 0; c < 64; ++c) {
    const float4 w = *(const float4*)(wt + c * 64 + d0);
    const float4 xv = *(const float4*)(xs + c * 64 + n_off);
    const float wa[4] = {w.x, w.y, w.z, w.w};
    const float xa[4] = {xv.x, xv.y, xv.z, xv.w};
#pragma unroll
    for (int i = 0; i < 4; ++i)
#pragma unroll
      for (int j = 0; j < 4; ++j)
        acc[i][j] = fmaf(wa[i], xa[j], acc[i][j]);
  }
  // Store bf16 quads (8 B/lane). Per wave+j, 16 nodes each get one full 64 B
  // span of their 128 B row => sector-complete writes.
#pragma unroll
  for (int j = 0; j < 4; ++j) {
    const int n = n0 + n_off + j;
    if (n < N) {
      ushort4 v;
      v.x = f2bf(fmaxf(acc[0][j], 0.f));
      v.y = f2bf(fmaxf(acc[1][j], 0.f));
      v.z = f2bf(fmaxf(acc[2][j], 0.f));
      v.w = f2bf(fmaxf(acc[3][j], 0.f));
      *(ushort4*)(y + ((size_t)b * N + n) * 64 + d0) = v;
    }
  }
}

// K2: gather-max over bf16 y rows, then out = relu(W2 @ [x; m] + b2).
// LDS: ins[128c][64n] bf16 + wt[128c][64o] bf16 = 32 KB -> 4-5 blocks/CU.
__global__ __launch_bounds__(256) void k2_gather_out(
    const float* __restrict__ x, const int* __restrict__ eidx,
    const unsigned short* __restrict__ y, const float* __restrict__ W2,
    const float* __restrict__ b2, float* __restrict__ out,
    int N, int K, const int* __restrict__ is64)
{
  __shared__ __align__(16) unsigned short ins[128 * 64];  // [c][n]
  __shared__ __align__(16) unsigned short wt[128 * 64];   // [c][o] = W2[o][c]
  const int t = threadIdx.x;
  const int nblk = (N + 63) >> 6;
  const int b = blockIdx.x / nblk;
  const int n0 = (blockIdx.x % nblk) << 6;

  {  // stage x tile -> ins rows 0..63 (bf16)
    const int n = t & 63;
    const int cw = (t >> 6) << 4;
    const bool valid = (n0 + n) < N;
    const float* xp = x + (size_t)b * 64 * N + n0 + n;
#pragma unroll
    for (int it = 0; it < 16; ++it) {
      const int c = cw + it;
      ins[c * 64 + n] = f2bf(valid ? xp[(size_t)c * N] : 0.0f);
    }
  }
#pragma unroll
  for (int it = 0; it < 32; ++it) {  // W2^T (cached strided reads)
    const int i = t + (it << 8);
    const int o = i & 63, c = i >> 6;
    wt[c * 64 + o] = f2bf(W2[o * 128 + c]);
  }

  {  // gather-max: thread = (node = t&63, 16-channel slice seg = t>>6)
    const int node = t & 63;
    const int seg = t >> 6;
    const int n = n0 + node;
    float m[16];
#pragma unroll
    for (int i = 0; i < 16; ++i) m[i] = 0.0f;
    if (n < N) {
      const int stride = (*is64) ? 2 : 1;
      const int* ep = eidx + (size_t)(b * N + n) * K * stride;
      const unsigned short* yb = y + (size_t)b * N * 64 + seg * 16;
      if (K == 9) {
        int jj[9];
#pragma unroll
        for (int k = 0; k < 9; ++k) jj[k] = ep[k * stride];
        // chunk 1: 5 rows in flight (10 x uint4)
        uint4 a[5], c2[5];
#pragma unroll
        for (int k = 0; k < 5; ++k) {
          const uint4* yr = (const uint4*)(yb + (size_t)jj[k] * 64);
          a[k] = yr[0]; c2[k] = yr[1];
        }
#pragma unroll
        for (int k = 0; k < 5; ++k) {
          const uint u[8] = {a[k].x, a[k].y, a[k].z, a[k].w,
                             c2[k].x, c2[k].y, c2[k].z, c2[k].w};
#pragma unroll
          for (int q = 0; q < 8; ++q) {
            m[2 * q]     = fmaxf(m[2 * q],     bflo(u[q]));
            m[2 * q + 1] = fmaxf(m[2 * q + 1], bfhi(u[q]));
          }
        }
        // chunk 2: remaining 4 rows
        uint4 d[4], e2[4];
#pragma unroll
        for (int k = 0; k < 4; ++k) {
          const uint4* yr = (const uint4*)(yb + (size_t)jj[5 + k] * 64);
          d[k] = yr[0]; e2[k] = yr[1];
        }
#pragma unroll
        for (int k = 0; k < 4; ++k) {
          const uint u[8] = {d[k].x, d[k].y, d[k].z, d[k].w,
                             e2[k].x, e2[k].y, e2[k].z, e2[k].w};
#pragma unroll
          for (int q = 0; q < 8; ++q) {
            m[2 * q]     = fmaxf(m[2 * q],     bflo(u[q]));
            m[2 * q + 1] = fmaxf(m[2 * q + 1], bfhi(u[q]));
          }
        }
      } else {
        for (int k = 0; k < K; ++k) {
          const int j = ep[k * stride];
          const uint4* yr = (const uint4*)(yb + (size_t)j * 64);
          const uint4 a0 = yr[0], a1 = yr[1];
          const uint u[8] = {a0.x, a0.y, a0.z, a0.w, a1.x, a1.y, a1.z, a1.w};
#pragma unroll
          for (int q = 0; q < 8; ++q) {
            m[2 * q]     = fmaxf(m[2 * q],     bflo(u[q]));
            m[2 * q + 1] = fmaxf(m[2 * q + 1], bfhi(u[q]));
          }
        }
      }
    }
    // LDS writes: bank = node>>1 -> 2-way aliasing (free)
#pragma unroll
    for (int i = 0; i < 16; ++i)
      ins[(64 + seg * 16 + i) * 64 + node] = f2bf(m[i]);
  }
  __syncthreads();

  // GEMM: out[64o x 64n] = W2[64x128] * ins[128x64], 4x4 tile/thread, bf16 ops
  const int n_off = (t & 15) << 2;
  const int o0 = (t >> 4) << 2;
  float acc[4][4];
#pragma unroll
  for (int i = 0; i < 4; ++i) {
    const float bv = b2[o0 + i];
#pragma unroll
    for (int j = 0; j < 4; ++j) acc[i][j] = bv;
  }
#pragma unroll 4
  for (int c = 0; c < 128; ++c) {
    const uint2 wq = *(const uint2*)(wt + c * 64 + o0);
    const uint2 xq = *(const uint2*)(ins + c * 64 + n_off);
    const float wa[4] = {bflo(wq.x), bfhi(wq.x), bflo(wq.y), bfhi(wq.y)};
    const float xa[4] = {bflo(xq.x), bfhi(xq.x), bflo(xq.y), bfhi(xq.y)};
#pragma unroll
    for (int i = 0; i < 4; ++i)
#pragma unroll
      for (int j = 0; j < 4; ++j)
        acc[i][j] = fmaf(wa[i], xa[j], acc[i][j]);
  }
  // Coalesced fp32 stores: out[(b*64+o)*N + n]
#pragma unroll
  for (int i = 0; i < 4; ++i) {
    const int o = o0 + i;
    float* op = out + (size_t)(b * 64 + o) * N + n0 + n_off;
    const float4 v = make_float4(fmaxf(acc[i][0], 0.f), fmaxf(acc[i][1], 0.f),
                                 fmaxf(acc[i][2], 0.f), fmaxf(acc[i][3], 0.f));
    if (n0 + n_off + 3 < N) {
      *(float4*)op = v;
    } else {
      const float va[4] = {v.x, v.y, v.z, v.w};
      for (int j = 0; j < 4; ++j)
        if (n0 + n_off + j < N) op[j] = va[j];
    }
  }
}

extern "C" void kernel_launch(void* const* d_in, const int* in_sizes, int n_in,
                              void* d_out, int out_size, void* d_ws, size_t ws_size,
                              hipStream_t stream) {
  const float* x  = (const float*)d_in[0];   // [B=2, C=64, N, 1]
  const int*   ei = (const int*)d_in[1];     // [2, B, N, K] (int64 or int32)
  const float* W1 = (const float*)d_in[2];   // [64, 64]
  const float* b1 = (const float*)d_in[3];   // [64]
  const float* W2 = (const float*)d_in[4];   // [64, 128]
  const float* b2 = (const float*)d_in[5];   // [64]
  float* out = (float*)d_out;                // [B, 64, N, 1]

  const int N = in_sizes[0] / 128;           // B*C = 128
  const int K = in_sizes[1] / (4 * N);       // 2*B = 4

  unsigned short* y = (unsigned short*)d_ws;            // bf16 [B,N,64] = 12.8 MB
  int* flag = (int*)((char*)d_ws + (size_t)2 * N * 64 * sizeof(unsigned short));

  const int nblk = (N + 63) >> 6;
  detect_idx_kernel<<<1, 64, 0, stream>>>(ei, flag);
  k1_node_mlp<<<2 * nblk, 256, 0, stream>>>(x, W1, b1, y, N);
  k2_gather_out<<<2 * nblk, 256, 0, stream>>>(x, ei, y, W2, b2, out, N, K, flag);
}

// Round 5
// 144.895 us; speedup vs baseline: 1.4611x; 1.2272x over previous
//
#include <hip/hip_runtime.h>
#include <cstddef>

typedef unsigned int uint;
typedef _Float16 half2v __attribute__((ext_vector_type(2)));
typedef __fp16 fp16v2 __attribute__((ext_vector_type(2)));
typedef unsigned short us2v __attribute__((ext_vector_type(2)));

union U32H2 { uint u; half2v h; fp16v2 g; us2v s; };

// pack two fp32 -> fp16 pair (single v_cvt_pkrtz instr)
__device__ __forceinline__ uint pkh2(float a, float b) {
  U32H2 v; v.g = __builtin_amdgcn_cvt_pkrtz(a, b); return v.u;
}
// packed max on u32-carried fp16 pairs. Valid for NON-NEGATIVE fp16 values
// (our y table is ReLU'd): fp16 ordering == unsigned ordering => v_pk_max_u16.
__device__ __forceinline__ uint hmax2u(uint a, uint b) {
  U32H2 x, y, r; x.u = a; y.u = b;
  r.s = __builtin_elementwise_max(x.s, y.s);
  return r.u;
}
// acc += dot(fp16 pair, fp16 pair)  [v_dot2_f32_f16]
__device__ __forceinline__ float fdot2(uint wa, uint xa, float acc) {
  U32H2 w, x; w.u = wa; x.u = xa;
#if __has_builtin(__builtin_amdgcn_fdot2)
  return __builtin_amdgcn_fdot2(w.h, x.h, acc, false);
#else
  return acc + (float)w.h[0] * (float)x.h[0] + (float)w.h[1] * (float)x.h[1];
#endif
}

// ---------------------------------------------------------------------------
// K1: y[b,n,:] = relu(W1 @ x[b,:,n] + b1), fp16 node-major rows (128 B each).
// LDS: x pairs [32][64] + W1^T pairs [32][64] = 16 KB.
// ---------------------------------------------------------------------------
__global__ __launch_bounds__(256) void k1_node_mlp(
    const float* __restrict__ x, const float* __restrict__ W1,
    const float* __restrict__ b1, unsigned short* __restrict__ y, int N)
{
  __shared__ __align__(16) uint xs2[32 * 64];  // [c2][n]: chans (2c2,2c2+1)
  __shared__ __align__(16) uint wt2[32 * 64];  // [c2][d]
  const int t = threadIdx.x;
  const int nblk = (N + 63) >> 6;
  const int b = blockIdx.x / nblk;
  const int n0 = (blockIdx.x % nblk) << 6;

#pragma unroll
  for (int it = 0; it < 8; ++it) {  // x tile: coalesced 256B rows, packed pairs
    const int i = t + (it << 8);
    const int n = i & 63, c2 = i >> 6;
    const bool valid = (n0 + n) < N;
    const float* xp = x + (size_t)b * 64 * N + n0 + n;
    const float a = valid ? xp[(size_t)(2 * c2) * N] : 0.0f;
    const float c = valid ? xp[(size_t)(2 * c2 + 1) * N] : 0.0f;
    xs2[c2 * 64 + n] = pkh2(a, c);
  }
#pragma unroll
  for (int it = 0; it < 8; ++it) {  // W1^T pairs (16 KB table, L2-hot)
    const int i = t + (it << 8);
    const int d = i & 63, c2 = i >> 6;
    wt2[c2 * 64 + d] = pkh2(W1[d * 64 + 2 * c2], W1[d * 64 + 2 * c2 + 1]);
  }
  __syncthreads();

  const int n_off = (t & 15) << 2;
  const int d0 = (t >> 4) << 2;
  float acc[4][4];
#pragma unroll
  for (int i = 0; i < 4; ++i) {
    const float bv = b1[d0 + i];
#pragma unroll
    for (int j = 0; j < 4; ++j) acc[i][j] = bv;
  }
#pragma unroll 8
  for (int c2 = 0; c2 < 32; ++c2) {
    const uint4 w = *(const uint4*)(wt2 + c2 * 64 + d0);
    const uint4 xv = *(const uint4*)(xs2 + c2 * 64 + n_off);
    const uint wa[4] = {w.x, w.y, w.z, w.w};
    const uint xa[4] = {xv.x, xv.y, xv.z, xv.w};
#pragma unroll
    for (int i = 0; i < 4; ++i)
#pragma unroll
      for (int j = 0; j < 4; ++j)
        acc[i][j] = fdot2(wa[i], xa[j], acc[i][j]);
  }
#pragma unroll
  for (int j = 0; j < 4; ++j) {  // store 4 fp16 (8 B) per node-row span
    const int n = n0 + n_off + j;
    if (n < N) {
      uint2 v;
      v.x = pkh2(fmaxf(acc[0][j], 0.f), fmaxf(acc[1][j], 0.f));
      v.y = pkh2(fmaxf(acc[2][j], 0.f), fmaxf(acc[3][j], 0.f));
      *(uint2*)(y + ((size_t)b * N + n) * 64 + d0) = v;
    }
  }
}

// ---------------------------------------------------------------------------
// K2: gather-max over fp16 y rows + out = relu(W2 @ [x; m] + b2).
// LDS: ins pairs [64][64] + W2^T pairs [64][64] = 32 KB.
// Per-wave inline int64/int32 layout detection (no flag kernel).
// ---------------------------------------------------------------------------
__global__ __launch_bounds__(256, 4) void k2_gather_out(
    const float* __restrict__ x, const int* __restrict__ eidx,
    const unsigned short* __restrict__ y, const float* __restrict__ W2,
    const float* __restrict__ b2, float* __restrict__ out, int N, int K)
{
  __shared__ __align__(16) uint ins2[64 * 64];  // rows 0..31: x, 32..63: m
  __shared__ __align__(16) uint wt2[64 * 64];   // [c2][o]
  const int t = threadIdx.x;
  const int nblk = (N + 63) >> 6;
  const int b = blockIdx.x / nblk;
  const int n0 = (blockIdx.x % nblk) << 6;

  // Layout detect: int64 little-endian => hi words (odd) all zero. L2-hot.
  const int lane = t & 63;
  const bool is64 = (__ballot(eidx[2 * lane + 1] == 0) == ~0ull);

  // Index loads issue now (no cross-kernel flag dependency).
  const int node = lane;
  const int seg = t >> 6;
  const int n = n0 + node;
  int jj[9];
  bool act = (n < N) && (K == 9);
  if (act) {
    const size_t r = (size_t)b * N + n;
    if (is64) {
      const uint2* p = (const uint2*)(eidx + r * 18);  // 8B-aligned always
#pragma unroll
      for (int k = 0; k < 9; ++k) jj[k] = (int)p[k].x;
    } else {
      const int* p = eidx + r * 9;
#pragma unroll
      for (int k = 0; k < 9; ++k) jj[k] = p[k];
    }
  }

  // Staging overlaps index-load latency.
#pragma unroll
  for (int it = 0; it < 8; ++it) {  // x pairs -> ins2 rows 0..31
    const int i = t + (it << 8);
    const int nn = i & 63, c2 = i >> 6;
    const bool valid = (n0 + nn) < N;
    const float* xp = x + (size_t)b * 64 * N + n0 + nn;
    const float a = valid ? xp[(size_t)(2 * c2) * N] : 0.0f;
    const float c = valid ? xp[(size_t)(2 * c2 + 1) * N] : 0.0f;
    ins2[c2 * 64 + nn] = pkh2(a, c);
  }
#pragma unroll
  for (int it = 0; it < 16; ++it) {  // W2^T pairs (32 KB table, L2-hot)
    const int i = t + (it << 8);
    const int o = i & 63, c2 = i >> 6;
    wt2[c2 * 64 + o] = pkh2(W2[o * 128 + 2 * c2], W2[o * 128 + 2 * c2 + 1]);
  }

  // Gather-max: all 9 rows' 32 B slices in flight at once (18 x uint4).
  uint m[8] = {0, 0, 0, 0, 0, 0, 0, 0};  // 8 fp16 pairs; relu'd y >= 0
  if (act) {
    const unsigned short* yb = y + (size_t)b * N * 64 + seg * 16;
    uint4 g[18];
#pragma unroll
    for (int k = 0; k < 9; ++k) {
      const uint4* yr = (const uint4*)(yb + (size_t)jj[k] * 64);
      g[2 * k] = yr[0];
      g[2 * k + 1] = yr[1];
    }
#pragma unroll
    for (int k = 0; k < 9; ++k) {
      m[0] = hmax2u(m[0], g[2 * k].x);
      m[1] = hmax2u(m[1], g[2 * k].y);
      m[2] = hmax2u(m[2], g[2 * k].z);
      m[3] = hmax2u(m[3], g[2 * k].w);
      m[4] = hmax2u(m[4], g[2 * k + 1].x);
      m[5] = hmax2u(m[5], g[2 * k + 1].y);
      m[6] = hmax2u(m[6], g[2 * k + 1].z);
      m[7] = hmax2u(m[7], g[2 * k + 1].w);
    }
  } else if (n < N) {  // generic K fallback
    const size_t r = (size_t)b * N + n;
    const unsigned short* yb = y + (size_t)b * N * 64 + seg * 16;
    for (int k = 0; k < K; ++k) {
      const int j = is64 ? (int)((const uint2*)(eidx + r * 2 * K))[k].x
                         : (eidx + r * K)[k];
      const uint4* yr = (const uint4*)(yb + (size_t)j * 64);
      const uint4 a0 = yr[0], a1 = yr[1];
      m[0] = hmax2u(m[0], a0.x); m[1] = hmax2u(m[1], a0.y);
      m[2] = hmax2u(m[2], a0.z); m[3] = hmax2u(m[3], a0.w);
      m[4] = hmax2u(m[4], a1.x); m[5] = hmax2u(m[5], a1.y);
      m[6] = hmax2u(m[6], a1.z); m[7] = hmax2u(m[7], a1.w);
    }
  }
  // m pairs -> ins2 rows 32..63; col = lane => 2-way bank aliasing (free)
#pragma unroll
  for (int q = 0; q < 8; ++q)
    ins2[(32 + seg * 8 + q) * 64 + node] = m[q];
  __syncthreads();

  // GEMM: out[64o x 64n] = W2[64x128] @ ins[128x64] via dot2, 4x4 tile/thread
  const int n_off = (t & 15) << 2;
  const int o0 = (t >> 4) << 2;
  float acc[4][4];
#pragma unroll
  for (int i = 0; i < 4; ++i) {
    const float bv = b2[o0 + i];
#pragma unroll
    for (int j = 0; j < 4; ++j) acc[i][j] = bv;
  }
#pragma unroll 8
  for (int c2 = 0; c2 < 64; ++c2) {
    const uint4 w = *(const uint4*)(wt2 + c2 * 64 + o0);
    const uint4 xv = *(const uint4*)(ins2 + c2 * 64 + n_off);
    const uint wa[4] = {w.x, w.y, w.z, w.w};
    const uint xa[4] = {xv.x, xv.y, xv.z, xv.w};
#pragma unroll
    for (int i = 0; i < 4; ++i)
#pragma unroll
      for (int j = 0; j < 4; ++j)
        acc[i][j] = fdot2(wa[i], xa[j], acc[i][j]);
  }
#pragma unroll
  for (int i = 0; i < 4; ++i) {  // coalesced fp32 stores
    const int o = o0 + i;
    float* op = out + (size_t)(b * 64 + o) * N + n0 + n_off;
    const float4 v = make_float4(fmaxf(acc[i][0], 0.f), fmaxf(acc[i][1], 0.f),
                                 fmaxf(acc[i][2], 0.f), fmaxf(acc[i][3], 0.f));
    if (n0 + n_off + 3 < N) {
      *(float4*)op = v;
    } else {
      const float va[4] = {v.x, v.y, v.z, v.w};
      for (int j = 0; j < 4; ++j)
        if (n0 + n_off + j < N) op[j] = va[j];
    }
  }
}

extern "C" void kernel_launch(void* const* d_in, const int* in_sizes, int n_in,
                              void* d_out, int out_size, void* d_ws, size_t ws_size,
                              hipStream_t stream) {
  const float* x  = (const float*)d_in[0];   // [B=2, C=64, N, 1]
  const int*   ei = (const int*)d_in[1];     // [2, B, N, K] (int64 or int32)
  const float* W1 = (const float*)d_in[2];   // [64, 64]
  const float* b1 = (const float*)d_in[3];   // [64]
  const float* W2 = (const float*)d_in[4];   // [64, 128]
  const float* b2 = (const float*)d_in[5];   // [64]
  float* out = (float*)d_out;                // [B, 64, N, 1]

  const int N = in_sizes[0] / 128;           // B*C = 128
  const int K = in_sizes[1] / (4 * N);       // 2*B = 4

  unsigned short* y = (unsigned short*)d_ws; // fp16 [B,N,64] = 12.8 MB

  const int nblk = (N + 63) >> 6;
  k1_node_mlp<<<2 * nblk, 256, 0, stream>>>(x, W1, b1, y, N);
  k2_gather_out<<<2 * nblk, 256, 0, stream>>>(x, ei, y, W2, b2, out, N, K);
}

// Round 6
// 116.926 us; speedup vs baseline: 1.8106x; 1.2392x over previous
//
#include <hip/hip_runtime.h>
#include <cstddef>

typedef unsigned int uint;
typedef _Float16 v8h __attribute__((ext_vector_type(8)));
typedef float v4f __attribute__((ext_vector_type(4)));
typedef __fp16 fp16v2 __attribute__((ext_vector_type(2)));
typedef unsigned short us2v __attribute__((ext_vector_type(2)));

union U32H2 { uint u; fp16v2 g; us2v s; };
union Frag8 { uint4 u4; uint u[4]; v8h h; };  // 8 fp16 = 4 VGPRs (MFMA A/B frag)

// pack two fp32 -> fp16 pair (v_cvt_pkrtz)
__device__ __forceinline__ uint pkh2(float a, float b) {
  U32H2 v; v.g = __builtin_amdgcn_cvt_pkrtz(a, b); return v.u;
}
// packed max on u32-carried fp16 pairs; valid for NON-NEGATIVE fp16 (ReLU'd y):
// fp16 ordering == unsigned ordering => v_pk_max_u16.
__device__ __forceinline__ uint hmax2u(uint a, uint b) {
  U32H2 x, y, r; x.u = a; y.u = b;
  r.s = __builtin_elementwise_max(x.s, y.s);
  return r.u;
}

// ---------------------------------------------------------------------------
// K1: y[b,n,:] = relu(W1 @ x[b,:,n] + b1), fp16 node-major rows (128 B).
// MFMA 16x16x32_f16: A = W1 (global->frags), B = x^T tile (LDS, n-major).
// ---------------------------------------------------------------------------
__global__ __launch_bounds__(256, 4) void k1_node_mlp(
    const float* __restrict__ x, const float* __restrict__ W1,
    const float* __restrict__ b1, uint* __restrict__ y, int N)
{
  __shared__ __align__(16) uint xlds[64 * 36];  // [n][c-pair], stride 36 dw (144 B)
  __shared__ __align__(16) uint ylds[64 * 34];  // [n][d-pair], stride 34 dw
  const int t = threadIdx.x;
  const int nblk = (N + 63) >> 6;
  const int b = blockIdx.x / nblk;
  const int n0 = (blockIdx.x % nblk) << 6;
  const int lane = t & 63;
  const int w = t >> 6;          // wave id -> d-strip
  const int node = t >> 2;       // staging row
  const int cg = t & 3;          // 16-channel group

  // ---- x staging: thread covers c = cg*16..+15 of node's row (two b128 writes)
  {
    const bool valid = (n0 + node) < N;
    const float* xp = x + (size_t)b * 64 * N + n0 + node;
    float xv[16];
#pragma unroll
    for (int i = 0; i < 16; ++i)
      xv[i] = valid ? xp[(size_t)(cg * 16 + i) * N] : 0.0f;
    uint4 p0, p1;
    p0.x = pkh2(xv[0], xv[1]);   p0.y = pkh2(xv[2], xv[3]);
    p0.z = pkh2(xv[4], xv[5]);   p0.w = pkh2(xv[6], xv[7]);
    p1.x = pkh2(xv[8], xv[9]);   p1.y = pkh2(xv[10], xv[11]);
    p1.z = pkh2(xv[12], xv[13]); p1.w = pkh2(xv[14], xv[15]);
    uint* dst = xlds + node * 36 + cg * 8;
    *(uint4*)dst = p0;
    *(uint4*)(dst + 4) = p1;
  }

  // ---- A-frags from W1 (L2-hot): lane row m = lane&15, k = (lane>>4)*8 + j
  Frag8 af[2];
  {
    const int d_row = w * 16 + (lane & 15);
    const int kb = (lane >> 4) * 8;
    const float* wp = W1 + d_row * 64 + kb;
#pragma unroll
    for (int kk = 0; kk < 2; ++kk) {
      const float4 fa = *(const float4*)(wp + kk * 32);
      const float4 fb = *(const float4*)(wp + kk * 32 + 4);
      af[kk].u4.x = pkh2(fa.x, fa.y);
      af[kk].u4.y = pkh2(fa.z, fa.w);
      af[kk].u4.z = pkh2(fb.x, fb.y);
      af[kk].u4.w = pkh2(fb.z, fb.w);
    }
  }
  __syncthreads();

  // ---- MFMA: D[d, n] per wave: d-strip = w*16, 4 n-tiles x 2 k-steps
  const int q = lane >> 4;
  const int cidx = lane & 15;
  const int d0 = w * 16;
  v4f acc[4];
  {
    v4f bi;
#pragma unroll
    for (int r = 0; r < 4; ++r) bi[r] = b1[d0 + q * 4 + r];
#pragma unroll
    for (int nt = 0; nt < 4; ++nt) acc[nt] = bi;
  }
#pragma unroll
  for (int nt = 0; nt < 4; ++nt) {
#pragma unroll
    for (int kk = 0; kk < 2; ++kk) {
      Frag8 bf;
      bf.u4 = *(const uint4*)(xlds + (nt * 16 + cidx) * 36 + kk * 16 + q * 4);
      acc[nt] = __builtin_amdgcn_mfma_f32_16x16x32_f16(af[kk].h, bf.h, acc[nt], 0, 0, 0);
    }
  }

  // ---- epilogue: relu, pack, LDS transpose, coalesced 128 B-row stores
#pragma unroll
  for (int nt = 0; nt < 4; ++nt) {
    const int nn = nt * 16 + cidx;
    const uint p01 = pkh2(fmaxf(acc[nt][0], 0.f), fmaxf(acc[nt][1], 0.f));
    const uint p23 = pkh2(fmaxf(acc[nt][2], 0.f), fmaxf(acc[nt][3], 0.f));
    ylds[nn * 34 + (d0 >> 1) + 2 * q] = p01;
    ylds[nn * 34 + (d0 >> 1) + 2 * q + 1] = p23;
  }
  __syncthreads();
#pragma unroll
  for (int p = 0; p < 4; ++p) {
    const int f = t + (p << 8);
    const int nn = f >> 4, ch = f & 15;
    if (n0 + nn < N) {
      const uint2 v = *(const uint2*)(ylds + nn * 34 + ch * 2);
      *(uint2*)(y + ((size_t)b * N + n0 + nn) * 32 + ch * 2) = v;
    }
  }
}

// ---------------------------------------------------------------------------
// K2: gather-max over fp16 y rows + out = relu(W2 @ [x; m] + b2) via MFMA.
// B-tile [64 n][128 c] fp16 in LDS (stride 272 B); A = W2 global->frags.
// ---------------------------------------------------------------------------
__global__ __launch_bounds__(256, 4) void k2_gather_out(
    const float* __restrict__ x, const int* __restrict__ eidx,
    const uint* __restrict__ y, const float* __restrict__ W2,
    const float* __restrict__ b2, float* __restrict__ out, int N, int K)
{
  __shared__ __align__(16) uint blds[64 * 68];  // [n][c-pair], stride 68 dw (272 B)
  const int t = threadIdx.x;
  const int nblk = (N + 63) >> 6;
  const int b = blockIdx.x / nblk;
  const int n0 = (blockIdx.x % nblk) << 6;
  const int lane = t & 63;
  const int w = t >> 6;
  const int node = t >> 2;   // staging/gather row; 4 adjacent lanes = 4 c-segs
  const int cg = t & 3;
  const int n = n0 + node;

  // int64 vs int32 layout: little-endian int64 => odd words all zero (L2-hot)
  const bool is64 = (__ballot(eidx[2 * lane + 1] == 0) == ~0ull);

  // ---- neighbor indices
  int jj[9];
  const bool act = (n < N) && (K == 9);
  if (act) {
    const size_t r = (size_t)b * N + n;
    if (is64) {
      const uint2* p = (const uint2*)eidx + r * 9;
#pragma unroll
      for (int k = 0; k < 9; ++k) jj[k] = (int)p[k].x;
    } else {
      const int* p = eidx + r * 9;
#pragma unroll
      for (int k = 0; k < 9; ++k) jj[k] = p[k];
    }
  }

  // ---- x staging -> blds rows, c in [0,64)
  {
    const bool valid = n < N;
    const float* xp = x + (size_t)b * 64 * N + n0 + node;
    float xv[16];
#pragma unroll
    for (int i = 0; i < 16; ++i)
      xv[i] = valid ? xp[(size_t)(cg * 16 + i) * N] : 0.0f;
    uint4 p0, p1;
    p0.x = pkh2(xv[0], xv[1]);   p0.y = pkh2(xv[2], xv[3]);
    p0.z = pkh2(xv[4], xv[5]);   p0.w = pkh2(xv[6], xv[7]);
    p1.x = pkh2(xv[8], xv[9]);   p1.y = pkh2(xv[10], xv[11]);
    p1.z = pkh2(xv[12], xv[13]); p1.w = pkh2(xv[14], xv[15]);
    uint* dst = blds + node * 68 + cg * 8;
    *(uint4*)dst = p0;
    *(uint4*)(dst + 4) = p1;
  }

  // ---- A-frags from W2 (global, L2-hot)
  Frag8 af[4];
  {
    const int o_row = w * 16 + (lane & 15);
    const int kb = (lane >> 4) * 8;
    const float* wp = W2 + o_row * 128 + kb;
#pragma unroll
    for (int kk = 0; kk < 4; ++kk) {
      const float4 fa = *(const float4*)(wp + kk * 32);
      const float4 fb = *(const float4*)(wp + kk * 32 + 4);
      af[kk].u4.x = pkh2(fa.x, fa.y);
      af[kk].u4.y = pkh2(fa.z, fa.w);
      af[kk].u4.z = pkh2(fb.x, fb.y);
      af[kk].u4.w = pkh2(fb.z, fb.w);
    }
  }

  // ---- gather-max: thread covers c-seg cg of its node; 4 adjacent lanes read
  // one full 128 B y row together. Two batches (5+4 rows) of uint4 loads.
  uint m[8] = {0, 0, 0, 0, 0, 0, 0, 0};
  if (act) {
    const uint* yb = y + (size_t)b * N * 32 + cg * 8;
    uint4 g[10];
#pragma unroll
    for (int k = 0; k < 5; ++k) {
      const uint* base = yb + (size_t)jj[k] * 32;
      g[2 * k] = *(const uint4*)base;
      g[2 * k + 1] = *(const uint4*)(base + 4);
    }
#pragma unroll
    for (int k = 0; k < 5; ++k) {
      m[0] = hmax2u(m[0], g[2 * k].x); m[1] = hmax2u(m[1], g[2 * k].y);
      m[2] = hmax2u(m[2], g[2 * k].z); m[3] = hmax2u(m[3], g[2 * k].w);
      m[4] = hmax2u(m[4], g[2 * k + 1].x); m[5] = hmax2u(m[5], g[2 * k + 1].y);
      m[6] = hmax2u(m[6], g[2 * k + 1].z); m[7] = hmax2u(m[7], g[2 * k + 1].w);
    }
#pragma unroll
    for (int k = 0; k < 4; ++k) {
      const uint* base = yb + (size_t)jj[5 + k] * 32;
      g[2 * k] = *(const uint4*)base;
      g[2 * k + 1] = *(const uint4*)(base + 4);
    }
#pragma unroll
    for (int k = 0; k < 4; ++k) {
      m[0] = hmax2u(m[0], g[2 * k].x); m[1] = hmax2u(m[1], g[2 * k].y);
      m[2] = hmax2u(m[2], g[2 * k].z); m[3] = hmax2u(m[3], g[2 * k].w);
      m[4] = hmax2u(m[4], g[2 * k + 1].x); m[5] = hmax2u(m[5], g[2 * k + 1].y);
      m[6] = hmax2u(m[6], g[2 * k + 1].z); m[7] = hmax2u(m[7], g[2 * k + 1].w);
    }
  } else if (n < N) {  // generic-K fallback
    const size_t r = (size_t)b * N + n;
    const uint* yb = y + (size_t)b * N * 32 + cg * 8;
    for (int k = 0; k < K; ++k) {
      const int j = is64 ? (int)((const uint2*)eidx + r * K)[k].x
                         : (eidx + r * K)[k];
      const uint* base = yb + (size_t)j * 32;
      const uint4 a0 = *(const uint4*)base, a1 = *(const uint4*)(base + 4);
      m[0] = hmax2u(m[0], a0.x); m[1] = hmax2u(m[1], a0.y);
      m[2] = hmax2u(m[2], a0.z); m[3] = hmax2u(m[3], a0.w);
      m[4] = hmax2u(m[4], a1.x); m[5] = hmax2u(m[5], a1.y);
      m[6] = hmax2u(m[6], a1.z); m[7] = hmax2u(m[7], a1.w);
    }
  }
  {
    uint* dst = blds + node * 68 + 32 + cg * 8;  // c in [64,128)
    uint4 v0; v0.x = m[0]; v0.y = m[1]; v0.z = m[2]; v0.w = m[3];
    uint4 v1; v1.x = m[4]; v1.y = m[5]; v1.z = m[6]; v1.w = m[7];
    *(uint4*)dst = v0;
    *(uint4*)(dst + 4) = v1;
  }
  __syncthreads();

  // ---- MFMA: D[o, n] per wave: o-strip w*16, 4 n-tiles x 4 k-steps
  const int q = lane >> 4;
  const int cidx = lane & 15;
  const int o0 = w * 16;
  v4f acc[4];
  {
    v4f bi;
#pragma unroll
    for (int r = 0; r < 4; ++r) bi[r] = b2[o0 + q * 4 + r];
#pragma unroll
    for (int nt = 0; nt < 4; ++nt) acc[nt] = bi;
  }
#pragma unroll
  for (int nt = 0; nt < 4; ++nt) {
#pragma unroll
    for (int kk = 0; kk < 4; ++kk) {
      Frag8 bf;
      bf.u4 = *(const uint4*)(blds + (nt * 16 + cidx) * 68 + kk * 16 + q * 4);
      acc[nt] = __builtin_amdgcn_mfma_f32_16x16x32_f16(af[kk].h, bf.h, acc[nt], 0, 0, 0);
    }
  }

  // ---- epilogue: relu + store; lanes cidx consecutive -> 64 B segments
#pragma unroll
  for (int nt = 0; nt < 4; ++nt) {
    const int nn = n0 + nt * 16 + cidx;
    if (nn < N) {
#pragma unroll
      for (int r = 0; r < 4; ++r) {
        const int o = o0 + q * 4 + r;
        out[(size_t)(b * 64 + o) * N + nn] = fmaxf(acc[nt][r], 0.f);
      }
    }
  }
}

extern "C" void kernel_launch(void* const* d_in, const int* in_sizes, int n_in,
                              void* d_out, int out_size, void* d_ws, size_t ws_size,
                              hipStream_t stream) {
  const float* x  = (const float*)d_in[0];   // [B=2, C=64, N, 1]
  const int*   ei = (const int*)d_in[1];     // [2, B, N, K] (int64 or int32)
  const float* W1 = (const float*)d_in[2];   // [64, 64]
  const float* b1 = (const float*)d_in[3];   // [64]
  const float* W2 = (const float*)d_in[4];   // [64, 128]
  const float* b2 = (const float*)d_in[5];   // [64]
  float* out = (float*)d_out;                // [B, 64, N, 1]

  const int N = in_sizes[0] / 128;           // B*C = 128
  const int K = in_sizes[1] / (4 * N);       // 2*B = 4

  uint* y = (uint*)d_ws;                     // fp16-pair table [B,N,32 dw] = 12.8 MB

  const int nblk = (N + 63) >> 6;
  k1_node_mlp<<<2 * nblk, 256, 0, stream>>>(x, W1, b1, y, N);
  k2_gather_out<<<2 * nblk, 256, 0, stream>>>(x, ei, y, W2, b2, out, N, K);
}